// Round 2
// baseline (357.665 us; speedup 1.0000x reference)
//
#include <hip/hip_runtime.h>

// Guided filter, guide==input (ref never used). 96 images of 512x512 f32.
// Fully fused single kernel, no HBM intermediates.
// Block = 128 threads x 4 cols = full 512-wide strip; streams a band of
// BH=64 output rows. Vertical running sums in registers; horizontal 17-tap
// box via padded LDS rows (aligned b128 window + sliding sum); A/b kept in
// a 17-row LDS ring (thread-private columns) for the fused second box.
// 2 barriers/step (3rd proven redundant); rcp instead of f32 div;
// one-step prefetch of the vertical-sum operand rows.

#define RR   8
#define DD   17          // 2R+1
#define WW   512
#define HH   512
#define BHH  64          // 8 bands/image -> 768 blocks = 3/CU balanced
#define NT   128         // threads per block
#define CPT  4           // cols per thread
#define PADW (WW + 2*RR)
#define FEPS 1e-8f

union F4 { float4 v; float f[4]; };

__device__ __forceinline__ float frcp(float a) { return __builtin_amdgcn_rcpf(a); }

__global__ __launch_bounds__(NT) void gf_kernel(
    const float* __restrict__ x, float* __restrict__ out)
{
    __shared__ float lv1[PADW], lv2[PADW], lva[PADW], lvb[PADW];
    __shared__ float aring[DD][WW], bring[DD][WW];   // 69.6 KB (78.1 KB total)

    const int tid = threadIdx.x;
    const int img = blockIdx.y;
    const int r0  = blockIdx.x * BHH;
    const float* px = x   + (size_t)img * (HH * WW);
    float*       po = out + (size_t)img * (HH * WW);
    const int c0 = tid * CPT;

    // zero horizontal pads once (truncated window: out-of-image cols add 0);
    // first in-loop barrier orders these before any window read.
    if (tid < RR) {
        lv1[tid] = 0.f; lv2[tid] = 0.f; lva[tid] = 0.f; lvb[tid] = 0.f;
        lv1[RR + WW + tid] = 0.f; lv2[RR + WW + tid] = 0.f;
        lva[RR + WW + tid] = 0.f; lvb[RR + WW + tid] = 0.f;
    }

    // per-column horizontal window counts (clamped)
    float inv_nx[CPT];
#pragma unroll
    for (int k = 0; k < CPT; ++k) {
        int c  = c0 + k;
        int nx = min(WW - 1, c + RR) - max(0, c - RR) + 1;
        inv_nx[k] = frcp((float)nx);
    }

    float v1[CPT] = {0.f,0.f,0.f,0.f}, v2[CPT] = {0.f,0.f,0.f,0.f};
    float va[CPT] = {0.f,0.f,0.f,0.f}, vb[CPT] = {0.f,0.f,0.f,0.f};

    const int rstart  = max(0, r0 - 2 * RR);   // first x row entering V1/V2
    const int rstart2 = max(0, r0 - RR);       // first A row entering VA/VB
    const int i2max   = r0 + BHH - 1;          // last output row of this band
    const int i1max   = min(HH - 1, i2max + RR);
    const int rend    = i2max + 2 * RR;        // virtual rows past H-1 included

    // one-step prefetch registers for the vertical-sum operand rows
    F4 xr_cur, xo_cur;
    xr_cur.v = make_float4(0.f,0.f,0.f,0.f);
    xo_cur.v = make_float4(0.f,0.f,0.f,0.f);
    if (rstart < HH) xr_cur.v = *(const float4*)(px + (size_t)rstart * WW + c0);
    // subV is false at r==rstart, so xo_cur needs no initial load.

#pragma unroll 1
    for (int r = rstart; r <= rend; ++r) {
        const int  i1   = r - RR;       // A/b row produced this step
        const int  i2   = r - 2 * RR;   // output row produced this step
        const bool addV = (r < HH);
        const bool subV = (r - DD >= rstart);
        const bool addA = (i1 >= rstart2) && (i1 <= i1max);
        const bool subA = (i1 - DD >= rstart2);
        const bool st2  = (i2 >= r0);   // i2 <= i2max guaranteed by rend

        // issue next step's vertical-sum rows + this step's output-row read.
        // xr_nxt is the only HBM/L3-cold stream; its latency hides under the
        // two barriers of THIS step. xi has natural slack to stage 2.
        const int rn = r + 1;
        const bool addVn = (rn < HH) && (rn <= rend);
        const bool subVn = (rn - DD >= rstart) && (rn <= rend);
        F4 xr_nxt, xo_nxt, xi;
        xr_nxt.v = xr_cur.v; xo_nxt.v = xo_cur.v;
        if (addVn) xr_nxt.v = *(const float4*)(px + (size_t)rn * WW + c0);
        if (subVn) xo_nxt.v = *(const float4*)(px + (size_t)(rn - DD) * WW + c0);
        if (st2)   xi.v     = *(const float4*)(px + (size_t)i2 * WW + c0);

        // vertical running sums of x, x^2
#pragma unroll
        for (int k = 0; k < CPT; ++k) {
            if (addV) { v1[k] += xr_cur.f[k]; v2[k] += xr_cur.f[k] * xr_cur.f[k]; }
            if (subV) { v1[k] -= xo_cur.f[k]; v2[k] -= xo_cur.f[k] * xo_cur.f[k]; }
        }
        {
            F4 a, b;
#pragma unroll
            for (int k = 0; k < CPT; ++k) { a.f[k] = v1[k]; b.f[k] = v2[k]; }
            *(float4*)&lv1[RR + c0] = a.v;
            *(float4*)&lv2[RR + c0] = b.v;
        }
        __syncthreads();   // barrier A: lv1/lv2 visible (also fences prior
                           // step's lva/lvb readers vs this step's writers)

        // ---- stage 1: horizontal box of V1/V2 -> A,b row i1; ring + VA/VB
        if (addA || subA) {
            const int slot = i1 >= 0 ? (i1 % DD) : ((i1 + DD) % DD); // i1-DD maps to same slot
            F4 olda, oldb;
            if (subA) {   // ring columns are thread-private: no race
                olda.v = *(float4*)&aring[slot][c0];
                oldb.v = *(float4*)&bring[slot][c0];
            }
            if (addA) {
                float w1[CPT + 16], w2[CPT + 16];
#pragma unroll
                for (int j = 0; j < 5; ++j) {
                    F4 t1, t2;
                    t1.v = *(float4*)&lv1[c0 + 4 * j];   // 16B-aligned window
                    t2.v = *(float4*)&lv2[c0 + 4 * j];
#pragma unroll
                    for (int q = 0; q < 4; ++q) { w1[4*j+q] = t1.f[q]; w2[4*j+q] = t2.f[q]; }
                }
                float S1[CPT], S2[CPT];
                float s1 = 0.f, s2 = 0.f;
#pragma unroll
                for (int j = 0; j < DD; ++j) { s1 += w1[j]; s2 += w2[j]; }
                S1[0] = s1; S2[0] = s2;
#pragma unroll
                for (int k = 1; k < CPT; ++k) {
                    S1[k] = S1[k-1] - w1[k-1] + w1[k-1+DD];
                    S2[k] = S2[k-1] - w2[k-1] + w2[k-1+DD];
                }
                const int   ny1   = min(HH - 1, i1 + RR) - max(0, i1 - RR) + 1;
                const float invny = frcp((float)ny1);
                F4 Af, Bf;
#pragma unroll
                for (int k = 0; k < CPT; ++k) {
                    float invN = invny * inv_nx[k];
                    float mean = S1[k] * invN;
                    float ex2  = S2[k] * invN;
                    float var  = ex2 - mean * mean;
                    float A    = var * frcp(var + FEPS);   // cov_xy == var_x
                    float b    = mean - A * mean;
                    Af.f[k] = A; Bf.f[k] = b;
                    va[k] += A; vb[k] += b;
                }
                *(float4*)&aring[slot][c0] = Af.v;
                *(float4*)&bring[slot][c0] = Bf.v;
            }
            if (subA) {
#pragma unroll
                for (int k = 0; k < CPT; ++k) { va[k] -= olda.f[k]; vb[k] -= oldb.f[k]; }
            }
        }
        if (st2) {
            F4 a, b;
#pragma unroll
            for (int k = 0; k < CPT; ++k) { a.f[k] = va[k]; b.f[k] = vb[k]; }
            *(float4*)&lva[RR + c0] = a.v;
            *(float4*)&lvb[RR + c0] = b.v;
        }
        __syncthreads();   // barrier B: lva/lvb visible (also fences this
                           // step's lv1/lv2 readers vs next step's writers)

        // ---- stage 2: horizontal box of VA/VB -> output row i2
        if (st2) {
            float wa[CPT + 16], wb[CPT + 16];
#pragma unroll
            for (int j = 0; j < 5; ++j) {
                F4 t1, t2;
                t1.v = *(float4*)&lva[c0 + 4 * j];
                t2.v = *(float4*)&lvb[c0 + 4 * j];
#pragma unroll
                for (int q = 0; q < 4; ++q) { wa[4*j+q] = t1.f[q]; wb[4*j+q] = t2.f[q]; }
            }
            float SA[CPT], SB[CPT];
            float sa = 0.f, sb = 0.f;
#pragma unroll
            for (int j = 0; j < DD; ++j) { sa += wa[j]; sb += wb[j]; }
            SA[0] = sa; SB[0] = sb;
#pragma unroll
            for (int k = 1; k < CPT; ++k) {
                SA[k] = SA[k-1] - wa[k-1] + wa[k-1+DD];
                SB[k] = SB[k-1] - wb[k-1] + wb[k-1+DD];
            }
            const int   ny2   = min(HH - 1, i2 + RR) - max(0, i2 - RR) + 1;
            const float invny = frcp((float)ny2);
            F4 of;
#pragma unroll
            for (int k = 0; k < CPT; ++k) {
                float invN = invny * inv_nx[k];
                of.f[k] = (SA[k] * invN) * xi.f[k] + SB[k] * invN;
            }
            *(float4*)(po + (size_t)i2 * WW + c0) = of.v;
        }
        // no third barrier needed: barrier A of the next iteration orders
        // this step's lva/lvb reads before the next writes; barrier B above
        // orders this step's lv1/lv2 reads before the next writes.

        xr_cur.v = xr_nxt.v;
        xo_cur.v = xo_nxt.v;
    }
}

extern "C" void kernel_launch(void* const* d_in, const int* in_sizes, int n_in,
                              void* d_out, int out_size, void* d_ws, size_t ws_size,
                              hipStream_t stream) {
    const float* x  = (const float*)d_in[0];   // d_in[1] (ref) unused by reference
    float* out      = (float*)d_out;
    const int nimg  = in_sizes[0] / (HH * WW); // 4*8*3 = 96
    dim3 grid(HH / BHH, nimg);                 // 8 bands x 96 images = 768 blocks
    gf_kernel<<<grid, NT, 0, stream>>>(x, out);
}

// Round 4
// 276.004 us; speedup vs baseline: 1.2959x; 1.2959x over previous
//
#include <hip/hip_runtime.h>

// Guided filter, guide==input (ref never used). 96 images of 512x512 f32.
// Fully fused, RING-FREE: the 17-row A/b LDS ring is replaced by a second,
// 17-step-DELAYED pair of vertical running sums (V1d,V2d) from which the
// A/b row leaving the vertical window is RECOMPUTED (bitwise identical to
// what was added 17 steps earlier -> exact cancellation, same numerics as
// the previously-passing ring kernel).
// LDS: 6 row buffers = 12.7 KB  (was 78.3 KB) -> residency grid-limited.
// BH=32 -> 1536 blocks = 6 blocks/CU = 12 waves/CU (3/SIMD), was 4 waves/CU.
// (Resubmission of round-3 kernel: bench infra failed; no counters to act on.)

#define RR   8
#define DD   17          // 2R+1
#define WW   512
#define HH   512
#define BHH  32          // 16 bands/image x 96 = 1536 blocks = 6/CU
#define NT   128         // threads per block (2 waves)
#define CPT  4           // cols per thread
#define PADW (WW + 2*RR)
#define FEPS 1e-8f

union F4 { float4 v; float f[4]; };

__device__ __forceinline__ float frcp(float a) { return __builtin_amdgcn_rcpf(a); }

// Horizontal 17-tap box of the vertical-sum row in lsum1/lsum2 (padded, zeroed
// pads), then A/b math for row j. Same code path for the "add" (current) and
// "subtract" (delayed-recompute) instances -> identical DAG -> bitwise-equal
// results for the same row, so the running va/vb sums cancel exactly.
__device__ __forceinline__ void stage1(const float* __restrict__ lsum1,
                                       const float* __restrict__ lsum2,
                                       int j, int c0, const float* inv_nx,
                                       F4& Af, F4& Bf)
{
    float w1[CPT + 16], w2[CPT + 16];
#pragma unroll
    for (int q = 0; q < 5; ++q) {
        F4 t1, t2;
        t1.v = *(const float4*)&lsum1[c0 + 4 * q];   // 16B-aligned window
        t2.v = *(const float4*)&lsum2[c0 + 4 * q];
#pragma unroll
        for (int e = 0; e < 4; ++e) { w1[4*q+e] = t1.f[e]; w2[4*q+e] = t2.f[e]; }
    }
    float S1[CPT], S2[CPT];
    float s1 = 0.f, s2 = 0.f;
#pragma unroll
    for (int q = 0; q < DD; ++q) { s1 += w1[q]; s2 += w2[q]; }
    S1[0] = s1; S2[0] = s2;
#pragma unroll
    for (int k = 1; k < CPT; ++k) {
        S1[k] = S1[k-1] - w1[k-1] + w1[k-1+DD];
        S2[k] = S2[k-1] - w2[k-1] + w2[k-1+DD];
    }
    const int   ny    = min(HH - 1, j + RR) - max(0, j - RR) + 1;
    const float invny = frcp((float)ny);
#pragma unroll
    for (int k = 0; k < CPT; ++k) {
        float invN = invny * inv_nx[k];
        float mean = S1[k] * invN;
        float ex2  = S2[k] * invN;
        float var  = ex2 - mean * mean;
        float A    = var * frcp(var + FEPS);   // cov_xy == var_x (guide==input)
        Af.f[k] = A;
        Bf.f[k] = mean - A * mean;
    }
}

__global__ __launch_bounds__(NT, 3) void gf_kernel(
    const float* __restrict__ x, float* __restrict__ out)
{
    __shared__ float lv1[PADW], lv2[PADW];   // current vertical sums row
    __shared__ float ld1[PADW], ld2[PADW];   // 17-step-delayed vertical sums row
    __shared__ float lva[PADW], lvb[PADW];   // vertical running sums of A,b
    // total LDS = 6*528*4 = 12,672 B

    const int tid = threadIdx.x;
    const int img = blockIdx.y;
    const int r0  = blockIdx.x * BHH;
    const float* px = x   + (size_t)img * (HH * WW);
    float*       po = out + (size_t)img * (HH * WW);
    const int c0 = tid * CPT;

    // zero pads once (clamped window: out-of-image cols contribute 0)
    if (tid < RR) {
        lv1[tid] = 0.f; lv2[tid] = 0.f; ld1[tid] = 0.f; ld2[tid] = 0.f;
        lva[tid] = 0.f; lvb[tid] = 0.f;
        lv1[RR+WW+tid] = 0.f; lv2[RR+WW+tid] = 0.f;
        ld1[RR+WW+tid] = 0.f; ld2[RR+WW+tid] = 0.f;
        lva[RR+WW+tid] = 0.f; lvb[RR+WW+tid] = 0.f;
    }

    float inv_nx[CPT];
#pragma unroll
    for (int k = 0; k < CPT; ++k) {
        int c  = c0 + k;
        int nx = min(WW - 1, c + RR) - max(0, c - RR) + 1;
        inv_nx[k] = frcp((float)nx);
    }

    float v1[CPT]  = {0,0,0,0}, v2[CPT]  = {0,0,0,0};   // current V sums
    float v1d[CPT] = {0,0,0,0}, v2d[CPT] = {0,0,0,0};   // delayed V sums
    float va[CPT]  = {0,0,0,0}, vb[CPT]  = {0,0,0,0};   // A/b vertical sums

    const int rstart  = max(0, r0 - 2 * RR);
    const int rstart2 = max(0, r0 - RR);
    const int i2max   = r0 + BHH - 1;
    const int i1max   = min(HH - 1, i2max + RR);
    const int rend    = i2max + 2 * RR;

    // one-step prefetch of the only cold stream (leading row r)
    F4 xr_cur; xr_cur.v = make_float4(0,0,0,0);
    if (rstart < HH) xr_cur.v = *(const float4*)(px + (size_t)rstart * WW + c0);

#pragma unroll 1
    for (int r = rstart; r <= rend; ++r) {
        const int  i1   = r - RR;        // A/b row entering the window
        const int  jd   = i1 - DD;       // A/b row leaving (recomputed)
        const int  i2   = r - 2 * RR;    // output row
        const bool addV  = (r < HH);
        const bool subV  = (r - DD >= rstart);    // also: delayed-add of row r-DD
        const bool subVd = (r - 2*DD >= rstart);  // delayed-sub of row r-2*DD
        const bool addA  = (i1 >= rstart2) && (i1 <= i1max);
        const bool subA  = (jd >= rstart2);
        const bool st2   = (i2 >= r0);

        // ---- issue loads. xr (next row) is the only cold stream and is
        // prefetched one step ahead; xm/xdd/xi trail <=34 rows -> L1/L2/L3.
        const int rn = r + 1;
        F4 xr_nxt; xr_nxt.v = xr_cur.v;
        if (rn < HH && rn <= rend)
            xr_nxt.v = *(const float4*)(px + (size_t)rn * WW + c0);
        F4 xm, xdd, xi;
        if (subV)  xm.v  = *(const float4*)(px + (size_t)(r - DD)  * WW + c0);
        if (subVd) xdd.v = *(const float4*)(px + (size_t)(r - 2*DD)* WW + c0);
        if (st2)   xi.v  = *(const float4*)(px + (size_t)i2 * WW + c0);

        // ---- vertical running sums (order add-then-sub; the delayed pair
        // executes the IDENTICAL sequence 17 steps later -> bitwise equal)
#pragma unroll
        for (int k = 0; k < CPT; ++k) {
            if (addV)  { v1[k]  += xr_cur.f[k]; v2[k]  += xr_cur.f[k] * xr_cur.f[k]; }
            if (subV)  { v1[k]  -= xm.f[k];     v2[k]  -= xm.f[k] * xm.f[k]; }
            if (subV)  { v1d[k] += xm.f[k];     v2d[k] += xm.f[k] * xm.f[k]; }   // delayed add
            if (subVd) { v1d[k] -= xdd.f[k];    v2d[k] -= xdd.f[k] * xdd.f[k]; } // delayed sub
        }
        {
            F4 a, b, c, d;
#pragma unroll
            for (int k = 0; k < CPT; ++k) { a.f[k] = v1[k]; b.f[k] = v2[k]; c.f[k] = v1d[k]; d.f[k] = v2d[k]; }
            *(float4*)&lv1[RR + c0] = a.v;
            *(float4*)&lv2[RR + c0] = b.v;
            *(float4*)&ld1[RR + c0] = c.v;
            *(float4*)&ld2[RR + c0] = d.v;
        }
        __syncthreads();   // barrier A: lv*/ld* visible; also fences prior
                           // step's lva/lvb readers vs this step's writers

        // ---- stage 1 (current): A/b row i1 enters the vertical window
        if (addA) {
            F4 Af, Bf;
            stage1(lv1, lv2, i1, c0, inv_nx, Af, Bf);
#pragma unroll
            for (int k = 0; k < CPT; ++k) { va[k] += Af.f[k]; vb[k] += Bf.f[k]; }
        }
        // ---- stage 1 (delayed recompute): row jd leaves the window
        if (subA) {
            F4 Af, Bf;
            stage1(ld1, ld2, jd, c0, inv_nx, Af, Bf);
#pragma unroll
            for (int k = 0; k < CPT; ++k) { va[k] -= Af.f[k]; vb[k] -= Bf.f[k]; }
        }
        if (st2) {
            F4 a, b;
#pragma unroll
            for (int k = 0; k < CPT; ++k) { a.f[k] = va[k]; b.f[k] = vb[k]; }
            *(float4*)&lva[RR + c0] = a.v;
            *(float4*)&lvb[RR + c0] = b.v;
        }
        __syncthreads();   // barrier B: lva/lvb visible; also fences this
                           // step's lv*/ld* readers vs next step's writers

        // ---- stage 2: horizontal box of va/vb -> output row i2
        if (st2) {
            float wa[CPT + 16], wb[CPT + 16];
#pragma unroll
            for (int q = 0; q < 5; ++q) {
                F4 t1, t2;
                t1.v = *(const float4*)&lva[c0 + 4 * q];
                t2.v = *(const float4*)&lvb[c0 + 4 * q];
#pragma unroll
                for (int e = 0; e < 4; ++e) { wa[4*q+e] = t1.f[e]; wb[4*q+e] = t2.f[e]; }
            }
            float SA[CPT], SB[CPT];
            float sa = 0.f, sb = 0.f;
#pragma unroll
            for (int q = 0; q < DD; ++q) { sa += wa[q]; sb += wb[q]; }
            SA[0] = sa; SB[0] = sb;
#pragma unroll
            for (int k = 1; k < CPT; ++k) {
                SA[k] = SA[k-1] - wa[k-1] + wa[k-1+DD];
                SB[k] = SB[k-1] - wb[k-1] + wb[k-1+DD];
            }
            const int   ny2   = min(HH - 1, i2 + RR) - max(0, i2 - RR) + 1;
            const float invny = frcp((float)ny2);
            F4 of;
#pragma unroll
            for (int k = 0; k < CPT; ++k) {
                float invN = invny * inv_nx[k];
                of.f[k] = (SA[k] * invN) * xi.f[k] + SB[k] * invN;
            }
            *(float4*)(po + (size_t)i2 * WW + c0) = of.v;
        }
        // no third barrier: next iteration's barrier A orders this step's
        // lva/lvb reads before the next writes; barrier B above orders this
        // step's lv*/ld* reads before the next writes.

        xr_cur.v = xr_nxt.v;
    }
}

extern "C" void kernel_launch(void* const* d_in, const int* in_sizes, int n_in,
                              void* d_out, int out_size, void* d_ws, size_t ws_size,
                              hipStream_t stream) {
    const float* x  = (const float*)d_in[0];   // d_in[1] (ref) unused by reference
    float* out      = (float*)d_out;
    const int nimg  = in_sizes[0] / (HH * WW); // 4*8*3 = 96
    dim3 grid(HH / BHH, nimg);                 // 16 bands x 96 images = 1536 blocks
    gf_kernel<<<grid, NT, 0, stream>>>(x, out);
}

// Round 6
// 275.020 us; speedup vs baseline: 1.3005x; 1.0036x over previous
//
#include <hip/hip_runtime.h>

// Guided filter, guide==input (ref unused). 96 images of 512x512 f32.
// Ring-free delayed-recompute structure (verified round 4), upgraded:
//  - NT=64 single-wave blocks, CPT=8: one wave covers the 512-wide row.
//    Horizontal-halo amortization cuts LDS traffic per col by ~40%.
//  - Split even/odd-float4 LDS layout keeps every ds_{read,write}_b128 at
//    canonical 16B/lane stride (bank-conflict-free) despite 8 cols/lane.
//  - Wave-private LDS => s_waitcnt lgkmcnt(0) fences instead of s_barrier
//    (no vmcnt(0) drain => prefetched rows stay in flight across steps).
// Grid: 16 bands x 96 images = 1536 one-wave blocks = 6 waves/CU.
// (Resubmission: round-5 bench infra failed; desk-verified, no changes.)

#define RR   8
#define DD   17
#define WW   512
#define HH   512
#define BHH  32
#define NT   64
#define CPT  8
#define NSLOT 66          // 1 pad + 64 + 1 pad float4 slots per sub-buffer
#define FEPS 1e-8f

union F4 { float4 v; float f[4]; };

__device__ __forceinline__ float frcp(float a) { return __builtin_amdgcn_rcpf(a); }

// write-completion-before-read fence for wave-private LDS (rule #18 pattern)
#define LFENCE() do { asm volatile("s_waitcnt lgkmcnt(0)" ::: "memory"); \
                      __builtin_amdgcn_sched_barrier(0); } while (0)

// Gather the 24-float horizontal window [c0-8, c0+15] for lane l from a
// split buffer pair. Slots l, l+1, l+2 (pad-shifted) -> stride 16B/lane.
__device__ __forceinline__ void hwin(const float4* __restrict__ ev,
                                     const float4* __restrict__ od,
                                     int l, float* w)
{
    F4 a, b, c, d, e, g;
    a.v = ev[l];     b.v = od[l];
    c.v = ev[l + 1]; d.v = od[l + 1];
    e.v = ev[l + 2]; g.v = od[l + 2];
#pragma unroll
    for (int t = 0; t < 4; ++t) {
        w[t]      = a.f[t]; w[4 + t]  = b.f[t];
        w[8 + t]  = c.f[t]; w[12 + t] = d.f[t];
        w[16 + t] = e.f[t]; w[20 + t] = g.f[t];
    }
}

// Horizontal 17-tap box of vertical sums + A/b math for row j.
// Identical DAG for the current and delayed-recompute instances =>
// bitwise-equal outputs for the same row => exact cancellation in va/vb.
__device__ __forceinline__ void stage1(const float4* ev1, const float4* od1,
                                       const float4* ev2, const float4* od2,
                                       int j, int l, const float* inv_nx,
                                       float* Af, float* Bf)
{
    float w1[24], w2[24];
    hwin(ev1, od1, l, w1);
    hwin(ev2, od2, l, w2);
    float S1[CPT], S2[CPT];
    float s1 = 0.f, s2 = 0.f;
#pragma unroll
    for (int q = 0; q < DD; ++q) { s1 += w1[q]; s2 += w2[q]; }
    S1[0] = s1; S2[0] = s2;
#pragma unroll
    for (int k = 1; k < CPT; ++k) {
        S1[k] = S1[k-1] - w1[k-1] + w1[k-1+DD];
        S2[k] = S2[k-1] - w2[k-1] + w2[k-1+DD];
    }
    const int   ny    = min(HH - 1, j + RR) - max(0, j - RR) + 1;
    const float invny = frcp((float)ny);
#pragma unroll
    for (int k = 0; k < CPT; ++k) {
        float invN = invny * inv_nx[k];
        float mean = S1[k] * invN;
        float ex2  = S2[k] * invN;
        float var  = ex2 - mean * mean;
        float A    = var * frcp(var + FEPS);   // cov_xy == var_x (guide==input)
        Af[k] = A;
        Bf[k] = mean - A * mean;
    }
}

// sub-buffer ids: 0=v1 1=v2 2=v1d 3=v2d 4=va 5=vb
__global__ __launch_bounds__(NT, 2) void gf_kernel(
    const float* __restrict__ x, float* __restrict__ out)
{
    __shared__ float4 EV[6][NSLOT];
    __shared__ float4 OD[6][NSLOT];   // total 12,672 B

    const int l   = threadIdx.x;          // 0..63
    const int img = blockIdx.y;
    const int r0  = blockIdx.x * BHH;
    const float* px = x   + (size_t)img * (HH * WW);
    float*       po = out + (size_t)img * (HH * WW);
    const int c0 = l * CPT;

    // zero the 4 pad slots of each of the 6 buffers (24 float4 stores)
    if (l < 24) {
        const int buf = l >> 2, s = l & 3;
        const float4 z = make_float4(0.f, 0.f, 0.f, 0.f);
        if      (s == 0) EV[buf][0]         = z;
        else if (s == 1) OD[buf][0]         = z;
        else if (s == 2) EV[buf][NSLOT - 1] = z;
        else             OD[buf][NSLOT - 1] = z;
    }

    float inv_nx[CPT];
#pragma unroll
    for (int k = 0; k < CPT; ++k) {
        int c  = c0 + k;
        int nx = min(WW - 1, c + RR) - max(0, c - RR) + 1;
        inv_nx[k] = frcp((float)nx);
    }

    float v1[CPT]  = {0,0,0,0,0,0,0,0}, v2[CPT]  = {0,0,0,0,0,0,0,0};
    float v1d[CPT] = {0,0,0,0,0,0,0,0}, v2d[CPT] = {0,0,0,0,0,0,0,0};
    float va[CPT]  = {0,0,0,0,0,0,0,0}, vb[CPT]  = {0,0,0,0,0,0,0,0};

    const int rstart  = max(0, r0 - 2 * RR);
    const int rstart2 = max(0, r0 - RR);
    const int i2max   = r0 + BHH - 1;
    const int i1max   = min(HH - 1, i2max + RR);
    const int rend    = i2max + 2 * RR;

    // one-step-ahead prefetch of all three vertical-sum operand rows
    F4 xr_c[2], xm_c[2], xdd_c[2];
#pragma unroll
    for (int h = 0; h < 2; ++h) {
        xr_c[h].v = make_float4(0,0,0,0);
        xm_c[h].v = make_float4(0,0,0,0);
        xdd_c[h].v = make_float4(0,0,0,0);
    }
    {   // prime xr for the first step (xm/xdd unused until their guards fire;
        // rstart <= 495 < HH always, so this load is in-bounds)
        const float* p = px + (size_t)rstart * WW + c0;
        xr_c[0].v = *(const float4*)(p);
        xr_c[1].v = *(const float4*)(p + 4);
    }

#pragma unroll 1
    for (int r = rstart; r <= rend; ++r) {
        const int  i1    = r - RR;        // A/b row entering the window
        const int  jd    = i1 - DD;       // A/b row leaving (recomputed)
        const int  i2    = r - 2 * RR;    // output row
        const bool addV  = (r < HH);
        const bool subV  = (r - DD   >= rstart);
        const bool subVd = (r - 2*DD >= rstart);
        const bool addA  = (i1 >= rstart2) && (i1 <= i1max);
        const bool subA  = (jd >= rstart2);
        const bool st2   = (i2 >= r0);

        // prefetch next step's rows (stay in flight across both fences)
        const int rn = r + 1;
        F4 xr_n[2] = {xr_c[0], xr_c[1]};
        F4 xm_n[2] = {xm_c[0], xm_c[1]};
        F4 xdd_n[2] = {xdd_c[0], xdd_c[1]};
        if (rn < HH && rn <= rend) {
            const float* p = px + (size_t)rn * WW + c0;
            xr_n[0].v = *(const float4*)(p); xr_n[1].v = *(const float4*)(p + 4);
        }
        if (rn - DD >= rstart && rn <= rend) {
            const float* p = px + (size_t)(rn - DD) * WW + c0;
            xm_n[0].v = *(const float4*)(p); xm_n[1].v = *(const float4*)(p + 4);
        }
        if (rn - 2*DD >= rstart && rn <= rend) {
            const float* p = px + (size_t)(rn - 2*DD) * WW + c0;
            xdd_n[0].v = *(const float4*)(p); xdd_n[1].v = *(const float4*)(p + 4);
        }
        F4 xi[2];
        if (st2) {
            const float* p = px + (size_t)i2 * WW + c0;
            xi[0].v = *(const float4*)(p); xi[1].v = *(const float4*)(p + 4);
        }

        // vertical running sums (add-then-sub; delayed pair runs the
        // identical sequence 17 steps later -> bitwise equal)
#pragma unroll
        for (int k = 0; k < CPT; ++k) {
            const float xa = xr_c[k >> 2].f[k & 3];
            const float xb = xm_c[k >> 2].f[k & 3];
            const float xc = xdd_c[k >> 2].f[k & 3];
            if (addV)  { v1[k]  += xa; v2[k]  += xa * xa; }
            if (subV)  { v1[k]  -= xb; v2[k]  -= xb * xb; }
            if (subV)  { v1d[k] += xb; v2d[k] += xb * xb; }
            if (subVd) { v1d[k] -= xc; v2d[k] -= xc * xc; }
        }
        {   // publish rows to LDS (split layout: lo quad -> EV, hi quad -> OD)
            F4 t;
#pragma unroll
            for (int e = 0; e < 4; ++e) t.f[e] = v1[e];
            EV[0][1 + l] = t.v;
#pragma unroll
            for (int e = 0; e < 4; ++e) t.f[e] = v1[4 + e];
            OD[0][1 + l] = t.v;
#pragma unroll
            for (int e = 0; e < 4; ++e) t.f[e] = v2[e];
            EV[1][1 + l] = t.v;
#pragma unroll
            for (int e = 0; e < 4; ++e) t.f[e] = v2[4 + e];
            OD[1][1 + l] = t.v;
#pragma unroll
            for (int e = 0; e < 4; ++e) t.f[e] = v1d[e];
            EV[2][1 + l] = t.v;
#pragma unroll
            for (int e = 0; e < 4; ++e) t.f[e] = v1d[4 + e];
            OD[2][1 + l] = t.v;
#pragma unroll
            for (int e = 0; e < 4; ++e) t.f[e] = v2d[e];
            EV[3][1 + l] = t.v;
#pragma unroll
            for (int e = 0; e < 4; ++e) t.f[e] = v2d[4 + e];
            OD[3][1 + l] = t.v;
        }
        LFENCE();   // writes of v-rows complete before window reads

        if (addA) {
            float Af[CPT], Bf[CPT];
            stage1(EV[0], OD[0], EV[1], OD[1], i1, l, inv_nx, Af, Bf);
#pragma unroll
            for (int k = 0; k < CPT; ++k) { va[k] += Af[k]; vb[k] += Bf[k]; }
        }
        if (subA) {
            float Af[CPT], Bf[CPT];
            stage1(EV[2], OD[2], EV[3], OD[3], jd, l, inv_nx, Af, Bf);
#pragma unroll
            for (int k = 0; k < CPT; ++k) { va[k] -= Af[k]; vb[k] -= Bf[k]; }
        }
        if (st2) {
            F4 t;
#pragma unroll
            for (int e = 0; e < 4; ++e) t.f[e] = va[e];
            EV[4][1 + l] = t.v;
#pragma unroll
            for (int e = 0; e < 4; ++e) t.f[e] = va[4 + e];
            OD[4][1 + l] = t.v;
#pragma unroll
            for (int e = 0; e < 4; ++e) t.f[e] = vb[e];
            EV[5][1 + l] = t.v;
#pragma unroll
            for (int e = 0; e < 4; ++e) t.f[e] = vb[4 + e];
            OD[5][1 + l] = t.v;
        }
        LFENCE();   // va/vb writes complete before stage-2 window reads
                    // (also drains stage-1 reads before next iter's writes)

        if (st2) {
            float wa[24], wb[24];
            hwin(EV[4], OD[4], l, wa);
            hwin(EV[5], OD[5], l, wb);
            float SA[CPT], SB[CPT];
            float sa = 0.f, sb = 0.f;
#pragma unroll
            for (int q = 0; q < DD; ++q) { sa += wa[q]; sb += wb[q]; }
            SA[0] = sa; SB[0] = sb;
#pragma unroll
            for (int k = 1; k < CPT; ++k) {
                SA[k] = SA[k-1] - wa[k-1] + wa[k-1+DD];
                SB[k] = SB[k-1] - wb[k-1] + wb[k-1+DD];
            }
            const int   ny2   = min(HH - 1, i2 + RR) - max(0, i2 - RR) + 1;
            const float invny = frcp((float)ny2);
            F4 o0, o1;
#pragma unroll
            for (int k = 0; k < CPT; ++k) {
                float invN = invny * inv_nx[k];
                float ov   = (SA[k] * invN) * xi[k >> 2].f[k & 3] + SB[k] * invN;
                if (k < 4) o0.f[k] = ov; else o1.f[k - 4] = ov;
            }
            float* p = po + (size_t)i2 * WW + c0;
            *(float4*)(p)     = o0.v;
            *(float4*)(p + 4) = o1.v;
        }

        xr_c[0] = xr_n[0];  xr_c[1] = xr_n[1];
        xm_c[0] = xm_n[0];  xm_c[1] = xm_n[1];
        xdd_c[0] = xdd_n[0]; xdd_c[1] = xdd_n[1];
    }
}

extern "C" void kernel_launch(void* const* d_in, const int* in_sizes, int n_in,
                              void* d_out, int out_size, void* d_ws, size_t ws_size,
                              hipStream_t stream) {
    const float* x  = (const float*)d_in[0];   // d_in[1] (ref) unused
    float* out      = (float*)d_out;
    const int nimg  = in_sizes[0] / (HH * WW); // 96
    dim3 grid(HH / BHH, nimg);                 // 16 bands x 96 = 1536 blocks
    gf_kernel<<<grid, NT, 0, stream>>>(x, out);
}